// Round 1
// baseline (55.597 us; speedup 1.0000x reference)
//
#include <hip/hip_runtime.h>

#define W 512

// ---------------------------------------------------------------------------
// Kernel A: inclusive prefix sum along x (contiguous) for channel 0.
// One wave (64 lanes) per row of 512 floats. Lane l owns elements [8l, 8l+8).
// ---------------------------------------------------------------------------
__global__ __launch_bounds__(256) void rowscan_kernel(const float* __restrict__ in,
                                                      float* __restrict__ out,
                                                      int nrows) {
    const int gtid    = blockIdx.x * 256 + threadIdx.x;
    const int wave_id = gtid >> 6;            // global row index
    const int lane    = threadIdx.x & 63;
    if (wave_id >= nrows) return;

    const int b = wave_id >> 9;               // / 512
    const int y = wave_id & 511;              // % 512
    const size_t base = (size_t)b * (2 * W * W) + (size_t)y * W;  // channel 0

    const float4* __restrict__ ip = (const float4*)(in + base);
    float4 v0 = ip[lane * 2 + 0];
    float4 v1 = ip[lane * 2 + 1];

    // local inclusive scan of 8
    float a0 = v0.x;
    float a1 = a0 + v0.y;
    float a2 = a1 + v0.z;
    float a3 = a2 + v0.w;
    float a4 = a3 + v1.x;
    float a5 = a4 + v1.y;
    float a6 = a5 + v1.z;
    float a7 = a6 + v1.w;

    // wave-level inclusive scan of per-lane totals (64 lanes, 6 steps)
    float total = a7;
    float inc = total;
#pragma unroll
    for (int off = 1; off < 64; off <<= 1) {
        float t = __shfl_up(inc, off, 64);
        if (lane >= off) inc += t;
    }
    const float excl = inc - total;            // exclusive prefix for this lane

    float4 r0 = make_float4(a0 + excl, a1 + excl, a2 + excl, a3 + excl);
    float4 r1 = make_float4(a4 + excl, a5 + excl, a6 + excl, a7 + excl);

    float4* __restrict__ op = (float4*)(out + base);
    op[lane * 2 + 0] = r0;
    op[lane * 2 + 1] = r1;
}

// ---------------------------------------------------------------------------
// Kernel B: inclusive prefix sum along y (stride W) for channel 1.
// Block = 256 threads = 4 waves. Tile = 64 columns x 512 rows.
// Wave w owns rows [128w, 128w+128); lane = column (coalesced 256B/instr).
// Phase 1: segment sums -> LDS (wave 0 writes output directly, offset 0).
// Phase 2: waves 1-3 re-read segment (L2-hot) with offset and write.
// ---------------------------------------------------------------------------
__global__ __launch_bounds__(256) void colscan_kernel(const float* __restrict__ in,
                                                      float* __restrict__ out) {
    __shared__ float sums[4][64];

    const int tx   = threadIdx.x & 63;
    const int wv   = threadIdx.x >> 6;
    const int tile = blockIdx.x & 7;           // 8 column-tiles of 64
    const int b    = blockIdx.x >> 3;
    const int col  = tile * 64 + tx;

    const size_t base = (size_t)b * (2 * W * W) + (size_t)(W * W) + col; // channel 1
    const int y0 = wv * 128;
    const float* __restrict__ p = in  + base + (size_t)y0 * W;
    float*       __restrict__ q = out + base + (size_t)y0 * W;

    if (wv == 0) {
        // offset is zero: scan and write output in one pass, publish total
        float acc = 0.f;
#pragma unroll 8
        for (int y = 0; y < 128; ++y) {
            acc += p[(size_t)y * W];
            q[(size_t)y * W] = acc;
        }
        sums[0][tx] = acc;
    } else {
        float s = 0.f;
#pragma unroll 8
        for (int y = 0; y < 128; ++y) {
            s += p[(size_t)y * W];
        }
        sums[wv][tx] = s;
    }
    __syncthreads();

    if (wv > 0) {
        float acc = 0.f;
        for (int w2 = 0; w2 < wv; ++w2) acc += sums[w2][tx];
#pragma unroll 8
        for (int y = 0; y < 128; ++y) {
            acc += p[(size_t)y * W];
            q[(size_t)y * W] = acc;
        }
    }
}

extern "C" void kernel_launch(void* const* d_in, const int* in_sizes, int n_in,
                              void* d_out, int out_size, void* d_ws, size_t ws_size,
                              hipStream_t stream) {
    const float* in = (const float*)d_in[0];
    float* out = (float*)d_out;

    const int B = in_sizes[0] / (2 * W * W);   // 64
    const int nrows = B * W;                   // 32768 row scans (channel 0)

    // Kernel A: 4 rows (waves) per 256-thread block
    const int blocksA = (nrows + 3) / 4;       // 8192
    rowscan_kernel<<<blocksA, 256, 0, stream>>>(in, out, nrows);

    // Kernel B: one block per (image, 64-column tile)
    const int blocksB = B * (W / 64);          // 512
    colscan_kernel<<<blocksB, 256, 0, stream>>>(in, out);
}

// Round 2
// 55.542 us; speedup vs baseline: 1.0010x; 1.0010x over previous
//
#include <hip/hip_runtime.h>

#define W 512

// ---------------------------------------------------------------------------
// Kernel A: inclusive prefix sum along x (contiguous) for channel 0.
// One wave (64 lanes) per row of 512 floats. Lane l owns elements [8l, 8l+8).
// ---------------------------------------------------------------------------
__global__ __launch_bounds__(256) void rowscan_kernel(const float* __restrict__ in,
                                                      float* __restrict__ out,
                                                      int nrows) {
    const int gtid    = blockIdx.x * 256 + threadIdx.x;
    const int wave_id = gtid >> 6;            // global row index
    const int lane    = threadIdx.x & 63;
    if (wave_id >= nrows) return;

    const int b = wave_id >> 9;               // / 512
    const int y = wave_id & 511;              // % 512
    const size_t base = (size_t)b * (2 * W * W) + (size_t)y * W;  // channel 0

    const float4* __restrict__ ip = (const float4*)(in + base);
    float4 v0 = ip[lane * 2 + 0];
    float4 v1 = ip[lane * 2 + 1];

    // local inclusive scan of 8
    float a0 = v0.x;
    float a1 = a0 + v0.y;
    float a2 = a1 + v0.z;
    float a3 = a2 + v0.w;
    float a4 = a3 + v1.x;
    float a5 = a4 + v1.y;
    float a6 = a5 + v1.z;
    float a7 = a6 + v1.w;

    // wave-level inclusive scan of per-lane totals (64 lanes, 6 steps)
    float total = a7;
    float inc = total;
#pragma unroll
    for (int off = 1; off < 64; off <<= 1) {
        float t = __shfl_up(inc, off, 64);
        if (lane >= off) inc += t;
    }
    const float excl = inc - total;            // exclusive prefix for this lane

    float4 r0 = make_float4(a0 + excl, a1 + excl, a2 + excl, a3 + excl);
    float4 r1 = make_float4(a4 + excl, a5 + excl, a6 + excl, a7 + excl);

    float4* __restrict__ op = (float4*)(out + base);
    op[lane * 2 + 0] = r0;
    op[lane * 2 + 1] = r1;
}

// ---------------------------------------------------------------------------
// Kernel B: inclusive prefix sum along y (stride W) for channel 1.
// Block = 256 threads = 4 waves. Tile = 64 columns x 512 rows.
// Wave w owns rows [128w, 128w+128); lane = column (coalesced 256B/instr).
// Phase 1: segment sums -> LDS (wave 0 writes output directly, offset 0).
// Phase 2: waves 1-3 re-read segment (L2-hot) with offset and write.
// ---------------------------------------------------------------------------
__global__ __launch_bounds__(256) void colscan_kernel(const float* __restrict__ in,
                                                      float* __restrict__ out) {
    __shared__ float sums[4][64];

    const int tx   = threadIdx.x & 63;
    const int wv   = threadIdx.x >> 6;
    const int tile = blockIdx.x & 7;           // 8 column-tiles of 64
    const int b    = blockIdx.x >> 3;
    const int col  = tile * 64 + tx;

    const size_t base = (size_t)b * (2 * W * W) + (size_t)(W * W) + col; // channel 1
    const int y0 = wv * 128;
    const float* __restrict__ p = in  + base + (size_t)y0 * W;
    float*       __restrict__ q = out + base + (size_t)y0 * W;

    if (wv == 0) {
        // offset is zero: scan and write output in one pass, publish total
        float acc = 0.f;
#pragma unroll 8
        for (int y = 0; y < 128; ++y) {
            acc += p[(size_t)y * W];
            q[(size_t)y * W] = acc;
        }
        sums[0][tx] = acc;
    } else {
        float s = 0.f;
#pragma unroll 8
        for (int y = 0; y < 128; ++y) {
            s += p[(size_t)y * W];
        }
        sums[wv][tx] = s;
    }
    __syncthreads();

    if (wv > 0) {
        float acc = 0.f;
        for (int w2 = 0; w2 < wv; ++w2) acc += sums[w2][tx];
#pragma unroll 8
        for (int y = 0; y < 128; ++y) {
            acc += p[(size_t)y * W];
            q[(size_t)y * W] = acc;
        }
    }
}

extern "C" void kernel_launch(void* const* d_in, const int* in_sizes, int n_in,
                              void* d_out, int out_size, void* d_ws, size_t ws_size,
                              hipStream_t stream) {
    const float* in = (const float*)d_in[0];
    float* out = (float*)d_out;

    const int B = in_sizes[0] / (2 * W * W);   // 64
    const int nrows = B * W;                   // 32768 row scans (channel 0)

    // Kernel A: 4 rows (waves) per 256-thread block
    const int blocksA = (nrows + 3) / 4;       // 8192
    rowscan_kernel<<<blocksA, 256, 0, stream>>>(in, out, nrows);

    // Kernel B: one block per (image, 64-column tile)
    const int blocksB = B * (W / 64);          // 512
    colscan_kernel<<<blocksB, 256, 0, stream>>>(in, out);
}

// Round 3
// 43.228 us; speedup vs baseline: 1.2861x; 1.2848x over previous
//
#include <hip/hip_runtime.h>

#define W 512

// ---------------------------------------------------------------------------
// Fused kernel, 512 threads = 8 waves per block.
//
// Blocks [0, B*8):        column scan (channel 1). Tile = 64 cols x 512 rows.
//   Wave w owns rows [64w, 64w+64), lane = column (coalesced 256B/instr).
//   Single pass: segment held in 64 registers; segment sums exchanged via
//   LDS; offset added in-register; one read + one write per element.
//
// Blocks [B*8, B*8+B*W/8): row scan (channel 0). One wave per 512-float row.
//   Lane l owns elements [8l, 8l+8) via 2x float4; local scan of 8 +
//   6-step __shfl_up wave scan.
// ---------------------------------------------------------------------------
__global__ __launch_bounds__(512) void fused_scan_kernel(const float* __restrict__ in,
                                                         float* __restrict__ out,
                                                         int B) {
    __shared__ float sums[8][64];

    const int tx = threadIdx.x & 63;   // lane
    const int wv = threadIdx.x >> 6;   // wave 0..7
    const int nColBlocks = B * 8;

    if ((int)blockIdx.x < nColBlocks) {
        // ----- column scan (channel 1), single pass -----
        const int tile = blockIdx.x & 7;       // 8 column-tiles of 64
        const int b    = blockIdx.x >> 3;
        const int col  = tile * 64 + tx;

        const size_t base = (size_t)b * (2 * W * W) + (size_t)(W * W) + col;
        const int y0 = wv * 64;
        const float* __restrict__ p = in  + base + (size_t)y0 * W;
        float*       __restrict__ q = out + base + (size_t)y0 * W;

        float v[64];
        // 64 independent coalesced loads (static indexing -> registers)
#pragma unroll
        for (int y = 0; y < 64; ++y) v[y] = p[(size_t)y * W];

        // in-register inclusive scan of the segment
        float acc = 0.f;
#pragma unroll
        for (int y = 0; y < 64; ++y) { acc += v[y]; v[y] = acc; }

        sums[wv][tx] = acc;
        __syncthreads();

        // exclusive offset = sum of preceding waves' segment totals
        float off = 0.f;
        for (int w2 = 0; w2 < wv; ++w2) off += sums[w2][tx];

#pragma unroll
        for (int y = 0; y < 64; ++y) q[(size_t)y * W] = v[y] + off;
    } else {
        // ----- row scan (channel 0) -----
        const int rb  = (int)blockIdx.x - nColBlocks;
        const int row = rb * 8 + wv;           // global row in [0, B*W)
        const int b   = row >> 9;              // / 512
        const int y   = row & 511;             // % 512
        const size_t base = (size_t)b * (2 * W * W) + (size_t)y * W;

        const float4* __restrict__ ip = (const float4*)(in + base);
        float4 v0 = ip[tx * 2 + 0];
        float4 v1 = ip[tx * 2 + 1];

        float a0 = v0.x;
        float a1 = a0 + v0.y;
        float a2 = a1 + v0.z;
        float a3 = a2 + v0.w;
        float a4 = a3 + v1.x;
        float a5 = a4 + v1.y;
        float a6 = a5 + v1.z;
        float a7 = a6 + v1.w;

        float total = a7;
        float inc = total;
#pragma unroll
        for (int o = 1; o < 64; o <<= 1) {
            float t = __shfl_up(inc, o, 64);
            if (tx >= o) inc += t;
        }
        const float excl = inc - total;

        float4 r0 = make_float4(a0 + excl, a1 + excl, a2 + excl, a3 + excl);
        float4 r1 = make_float4(a4 + excl, a5 + excl, a6 + excl, a7 + excl);

        float4* __restrict__ op = (float4*)(out + base);
        op[tx * 2 + 0] = r0;
        op[tx * 2 + 1] = r1;
    }
}

extern "C" void kernel_launch(void* const* d_in, const int* in_sizes, int n_in,
                              void* d_out, int out_size, void* d_ws, size_t ws_size,
                              hipStream_t stream) {
    const float* in = (const float*)d_in[0];
    float* out = (float*)d_out;

    const int B = in_sizes[0] / (2 * W * W);   // 64
    const int colBlocks = B * 8;               // 512  (64-col tiles)
    const int rowBlocks = (B * W) / 8;         // 4096 (8 rows per block)

    fused_scan_kernel<<<colBlocks + rowBlocks, 512, 0, stream>>>(in, out, B);
}